// Round 19
// baseline (371.728 us; speedup 1.0000x reference)
//
#include <hip/hip_runtime.h>
#include <cstddef>

namespace {
constexpr int B_ = 16, C_ = 32, N_ = 1024, L_ = 24, CO_ = 64;

constexpr size_t S_OFF = (size_t)B_*CO_*N_*L_;            // 25165824 floats
constexpr size_t T_OFF = S_OFF + (size_t)B_*N_*N_;        // 41943040

// ---- workspace layout (f32 units) ----
constexpr size_t O_GCN  = 0;                              // gcn bf16 [B][N][26][64] (rawp aliases)
constexpr size_t O_XTLC = 13631488;                       // xT bf16 [B][N][24][32]
constexpr size_t O_XR   = 19922944;                       // x  bf16 [B][N][24][32]
constexpr size_t O_SUPB = 26214400;                       // supB packed bf16 (1M u16)
constexpr size_t O_LGB  = 26738688;                       // logits bf16 / part2 (early) / preB bf16 (late)
constexpr size_t O_F1T  = 38797312;
constexpr size_t O_F2T  = 39583744;
constexpr size_t O_F2S  = 39596032;                       // f2p packed bf16 (512K u16)
constexpr size_t O_GT   = 40120320;
constexpr size_t O_GS   = 40132608;                       // gsp packed bf16 (512K u16)
constexpr size_t O_CM   = 40656896;                       // colmax keys u32 [B][N]
constexpr size_t O_WAP  = 40673280;                       // GA weights packed (6144 u16)
constexpr size_t O_W2P  = 40676352;                       // GB weights packed (14336 u16)
constexpr size_t O_PART = 40683520;                       // [3072][2]
constexpr size_t O_BST  = 40689664;                       // [B][2]

// ---- d_out scratch (u16 units), region [0, S_OFF floats) dead until k_gb ----
constexpr size_t OS_A1  = 0;
constexpr size_t OS_A2  = OS_A1 + (size_t)B_*N_*N_;
constexpr size_t OS_XP  = OS_A2 + (size_t)B_*N_*N_;
constexpr size_t OS_SV  = OS_XP + (size_t)B_*N_*768;
constexpr size_t OS_SUP2= OS_SV + (size_t)N_*N_;          // sup2 bf16 row-major (1M u16)
constexpr size_t OS_SUPR= OS_SUP2 + (size_t)N_*N_;        // supports bf16 row-major (1M u16)
constexpr size_t OS_SUPA= OS_SUPR + (size_t)N_*N_;        // supA packed bf16 (1M u16)

typedef unsigned short u16;
typedef __attribute__((ext_vector_type(8))) short short8v;
typedef __attribute__((ext_vector_type(4))) short short4v;
typedef __attribute__((ext_vector_type(4))) float f32x4;

__device__ __forceinline__ u16 f2bf(float x) {
  unsigned u = __builtin_bit_cast(unsigned, x);
  return (u16)((u + 0x7fffu + ((u >> 16) & 1u)) >> 16);
}
__device__ __forceinline__ float bf2f(u16 v) {
  return __builtin_bit_cast(float, ((unsigned)v) << 16);
}
// monotonic float<->unsigned key (order-preserving; max on keys == max on floats)
__device__ __forceinline__ unsigned fkey(float f) {
  unsigned u = __builtin_bit_cast(unsigned, f);
  return (u & 0x80000000u) ? ~u : (u | 0x80000000u);
}
__device__ __forceinline__ float funkey(unsigned k) {
  unsigned u = (k & 0x80000000u) ? (k ^ 0x80000000u) : ~k;
  return __builtin_bit_cast(float, u);
}
__device__ __forceinline__ void gl_lds16(const void* g, void* l) {
  __builtin_amdgcn_global_load_lds(
      (const __attribute__((address_space(1))) unsigned int*)g,
      (__attribute__((address_space(3))) unsigned int*)l, 16, 0, 0);
}

// ---------------- fused stage 1: f1t + gsp + f2p + f2t partials + xr, one x pass ----------------
__global__ __launch_bounds__(256) void k_ff(const float* __restrict__ x,
    const float* __restrict__ t1w, const float* __restrict__ s1w,
    const float* __restrict__ w2s, const float* __restrict__ t2w,
    const float* __restrict__ sw, float* __restrict__ f1t,
    u16* __restrict__ gsp, u16* __restrict__ f2p,
    float* __restrict__ part2, u16* __restrict__ xr) {
  int blk = blockIdx.x;                              // B*128
  int b = blk >> 7, n0 = (blk & 127) << 3;
  __shared__ float ls[32*200];                       // [c][nl*25 + l], stride-25 pad
  __shared__ float tls[8*33];
  __shared__ float f1sL[200];                        // [nl*25 + l]
  int t = threadIdx.x;
  const float* xb = x + (size_t)b*C_*N_*L_;
  #pragma unroll
  for (int i = 0; i < 24; i++) {
    int flat = i*256 + t;
    int c = flat / 192, r = flat - c*192;
    int nl = r / 24, l = r - nl*24;
    ls[c*200 + nl*25 + l] = xb[((size_t)c*N_ + n0 + nl)*L_ + l];
  }
  __syncthreads();
  if (t < 192) {
    int nl = t / 24, l = t - (t/24)*24;
    float a1 = 0.f, a2 = 0.f;
    #pragma unroll
    for (int c = 0; c < C_; c++) {
      float v = ls[c*200 + nl*25 + l];
      a1 += v * t1w[c]; a2 += v * s1w[c];
    }
    f1t[((size_t)b*L_ + l)*N_ + n0 + nl] = a1;
    f1sL[nl*25 + l] = a2;
  }
  {
    int c = t >> 3, nl = t & 7;
    const float* lp = &ls[c*200 + nl*25];
    float a = 0.f;
    #pragma unroll
    for (int l = 0; l < L_; l++) a += lp[l] * w2s[l];
    tls[nl*33 + c] = a;
  }
  const float* twn = t2w + n0;
  #pragma unroll
  for (int i = 0; i < 3; i++) {
    int flat = t + 256*i;
    int c2 = flat / 24, l2 = flat - c2*24;
    float a2 = 0.f;
    #pragma unroll
    for (int nl2 = 0; nl2 < 8; nl2++)
      a2 += ls[c2*200 + nl2*25 + l2] * twn[nl2];
    part2[(size_t)blk*768 + flat] = a2;
  }
  // xr: bf16 copy of x in [n][l*32+c] order (coalesced 512B/wave writes)
  u16* xrb = xr + (size_t)(b*N_ + n0)*768;
  #pragma unroll
  for (int i = 0; i < 24; i++) {
    int flat = i*256 + t;
    int nl = flat / 768, r = flat - nl*768;
    int l = r >> 5, c = r & 31;
    xrb[flat] = f2bf(ls[c*200 + nl*25 + l]);
  }
  __syncthreads();
  // f2p: B-fragment layout for f2s[c][m]; m = n0 + (t>>5), c = t&31
  {
    int m = n0 + (t >> 5), c = t & 31;
    float v = tls[(t >> 5)*33 + c];
    f2p[(size_t)b*32768 + (size_t)(m >> 4)*512 +
        (((m & 15) | ((c >> 3) << 4)) << 3) + (c & 7)] = f2bf(v);
  }
  // gsp: A-fragment layout for g_s[n][c] = sum_l f1s[n][l]*sw[l*32+c]
  {
    int nl = t >> 5, cg = t & 31;
    const float* fl = &f1sL[nl*25];
    float ag = 0.f;
    #pragma unroll
    for (int l = 0; l < L_; l++) ag += fl[l] * sw[l*32 + cg];
    int n = n0 + nl;
    gsp[(size_t)b*32768 + (size_t)(n >> 4)*512 +
        (((n & 15) | ((cg >> 3) << 4)) << 3) + (cg & 7)] = f2bf(ag);
  }
}

// ---------------- merged: f2t reduce (blocks 0..47) + g_t (blocks 48..431) ----------------
__global__ __launch_bounds__(256) void k_aux(const float* __restrict__ part2,
    float* __restrict__ f2t, const float* __restrict__ f1t,
    const float* __restrict__ tw, float* __restrict__ g_t) {
  int blk = blockIdx.x;
  int t = threadIdx.x;
  if (blk < 48) {
    int idx = blk * 256 + t;                         // B*768 = 12288
    int b = idx / 768, cl = idx - b*768;
    const float* p = part2 + (size_t)b*98304 + cl;
    float s = 0.f;
    #pragma unroll 8
    for (int k = 0; k < 128; k++) s += p[(size_t)k*768];
    f2t[idx] = s;
    return;
  }
  int bl = blk - 48;                                 // 0..383 = B*L
  int nsub = t >> 5, c = t & 31;
  const float* f = f1t + (size_t)bl * N_;
  float a = 0.f;
  for (int i = 0; i < 128; i++) {
    int n = nsub + (i << 3);
    a += f[n] * tw[n*32 + c];
  }
  __shared__ float s[256];
  s[t] = a; __syncthreads();
  if (t < 128) s[t] += s[t + 128];
  __syncthreads();
  if (t < 64) s[t] += s[t + 64];
  __syncthreads();
  if (t < 32) g_t[(size_t)bl*32 + t] = s[t] + s[t + 32];
}

// ---------------- temporal attention ----------------
__global__ __launch_bounds__(576) void k_tatt(const float* __restrict__ g_t,
    const float* __restrict__ f2t, const float* __restrict__ tb,
    const float* __restrict__ tv, float* __restrict__ Tout) {
  int b = blockIdx.x; int tid = threadIdx.x;
  int l = tid / 24, q = tid % 24;
  __shared__ float rawS[576], logS[576], cmS[24], rmS[24], rsS[24];
  float acc = tb[tid];
  const float* g = g_t + ((size_t)b*L_ + l)*C_;
  const float* f = f2t + (size_t)b*C_*L_ + q;
  #pragma unroll
  for (int c = 0; c < C_; c++) acc += g[c] * f[(size_t)c*L_];
  rawS[tid] = 1.f / (1.f + expf(-acc));
  __syncthreads();
  float lg = 0.f;
  #pragma unroll
  for (int k = 0; k < L_; k++) lg += tv[l*L_ + k] * rawS[k*L_ + q];
  logS[tid] = lg;
  __syncthreads();
  if (l == 0) { float m = -3.4e38f; for (int mm = 0; mm < L_; mm++) m = fmaxf(m, logS[mm*L_ + q]); cmS[q] = m; }
  __syncthreads();
  float lc = lg - cmS[q];
  logS[tid] = lc;
  __syncthreads();
  if (q == 0) { float m = -3.4e38f; for (int qq = 0; qq < L_; qq++) m = fmaxf(m, logS[l*L_ + qq]); rmS[l] = m; }
  __syncthreads();
  float e = expf(lc - rmS[l]);
  logS[tid] = e;
  __syncthreads();
  if (q == 0) { float s = 0.f; for (int qq = 0; qq < L_; qq++) s += logS[l*L_ + qq]; rsS[l] = s; }
  __syncthreads();
  Tout[(size_t)b*576 + q*24 + l] = e / rsS[l];
}

// ---------------- raw_s via MFMA: sigmoid(gs @ f2s + s_b) -> packed rawp ----------------
__global__ __launch_bounds__(256) void k_rawsm(
    const u16* __restrict__ gsp, const u16* __restrict__ f2p,
    const float* __restrict__ sb, u16* __restrict__ rawp) {
  int b = blockIdx.z;
  int mg0 = blockIdx.y * 8;                          // n 16-groups
  int ng0 = blockIdx.x * 8;                          // m 16-groups
  const u16* A  = gsp + (size_t)b*32768;
  const u16* Bm = f2p + (size_t)b*32768;
  int tid = threadIdx.x;
  int w = tid >> 6, lane = tid & 63;
  int wr = w >> 1, wc = w & 1;
  int lm = lane & 15, hi = lane >> 4;
  __shared__ __align__(16) u16 smem[16*512];
  #pragma unroll
  for (int i = 0; i < 4; i++) {
    int f = w + 4*i;
    if (f < 8)
      gl_lds16(A + (size_t)(mg0 + f)*512 + (lane << 3), &smem[f*512]);
    else
      gl_lds16(Bm + (size_t)(ng0 + f - 8)*512 + (lane << 3), &smem[f*512]);
  }
  __syncthreads();
  f32x4 acc[4][4] = {};
  #pragma unroll
  for (int j = 0; j < 4; j++) {
    short8v bv = *(const short8v*)&smem[(8 + wc*4 + j)*512 + (lane << 3)];
    #pragma unroll
    for (int i = 0; i < 4; i++) {
      short8v av = *(const short8v*)&smem[(wr*4 + i)*512 + (lane << 3)];
      acc[i][j] = __builtin_amdgcn_mfma_f32_16x16x32_bf16(av, bv, acc[i][j], 0, 0, 0);
    }
  }
  u16* d = rawp + ((size_t)b << 20);
  #pragma unroll
  for (int i = 0; i < 4; i++) {
    int nb = (mg0 + wr*4 + i)*16 + hi*4;             // base row (k-dim of rawp)
    #pragma unroll
    for (int j = 0; j < 4; j++) {
      int m = (ng0 + wc*4 + j)*16 + lm;              // column
      const float* sbp = sb + (size_t)nb*N_ + m;
      u16 ov[4];
      #pragma unroll
      for (int r = 0; r < 4; r++) {
        float v2 = acc[i][j][r] + sbp[(size_t)r*N_];
        ov[r] = f2bf(1.f / (1.f + expf(-v2)));
      }
      int fi2 = ((nb >> 5) << 6) | (m >> 4);
      int lp  = (m & 15) | (((nb >> 3) & 3) << 4);
      *(unsigned long long*)&d[(size_t)fi2*512 + lp*8 + (nb & 7)] =
          *(unsigned long long*)ov;
    }
  }
}

// ---------------- pack s_v + supports(A/B/rowmajor) + weights + colmax zero ----------------
__global__ void k_pack_sv(const float* __restrict__ sv, u16* __restrict__ svp,
                          const float* __restrict__ sup, u16* __restrict__ supA,
                          u16* __restrict__ supB, u16* __restrict__ supR,
                          const float* __restrict__ gcn_w, const float* __restrict__ time_w,
                          const float* __restrict__ conv1_w, u16* __restrict__ WAp,
                          u16* __restrict__ W2p, unsigned* __restrict__ cmz) {
  int t = blockIdx.x * 256 + threadIdx.x;            // 131072
  int fi = t >> 6, l = t & 63;
  int mg = fi >> 5, kg = fi & 31;
  int row = (mg << 4) + (l & 15);
  int k   = (kg << 5) + ((l >> 4) << 3);
  {
    const float* s = sv + (size_t)row*N_ + k;
    const float* s2 = sup + (size_t)row*N_ + k;
    u16* d  = svp  + ((size_t)fi << 9) + (l << 3);
    u16* dA = supA + ((size_t)fi << 9) + (l << 3);
    u16* dR = supR + (size_t)row*N_ + k;
    #pragma unroll
    for (int j = 0; j < 8; j++) {
      u16 bv = f2bf(s2[j]);
      d[j] = f2bf(s[j]); dA[j] = bv; dR[j] = bv;
    }
  }
  {
    int kgB = fi >> 6, nbB = fi & 63;
    int colB = (nbB << 4) + (l & 15);
    int krB  = (kgB << 5) + ((l >> 4) << 3);
    u16* dB = supB + ((size_t)fi << 9) + (l << 3);
    #pragma unroll
    for (int j = 0; j < 8; j++) dB[j] = f2bf(sup[(size_t)(krB + j)*N_ + colB]);
  }
  if (t < 16384) cmz[t] = 0u;
  if (t < 6144) {
    int fi2 = t >> 9, l2 = (t >> 3) & 63, j2 = t & 7;
    int kg2 = fi2 >> 2, cf = fi2 & 3;
    int o = cf*16 + (l2 & 15), c = ((l2 >> 4) << 3) + j2;
    WAp[t] = f2bf(gcn_w[o*96 + c*3 + kg2]);
  }
  if (t < 14336) {
    int fi2 = t >> 9, l2 = (t >> 3) & 63, j2 = t & 7;
    int kg2 = fi2 >> 2, cf = fi2 & 3;
    int o2 = cf*16 + (l2 & 15), kk = ((l2 >> 4) << 3) + j2;
    float v;
    if (kg2 < 6) { int tt2 = kg2 >> 1, i = (kg2 & 1)*32 + kk; v = time_w[o2*192 + i*3 + tt2]; }
    else v = conv1_w[o2*32 + kk];
    W2p[t] = f2bf(v);
  }
}

// ---------------- sup2 = 2*(sup@sup) - I  (bf16 row-major out) ----------------
__global__ __launch_bounds__(256) void k_sup2(const u16* __restrict__ Ap,
    const u16* __restrict__ Bp, u16* __restrict__ D) {
  int mg0 = blockIdx.y * 8, ng0 = blockIdx.x * 8;
  constexpr int Kg = 32, Ng = 64;
  int tid = threadIdx.x;
  int w = tid >> 6, lane = tid & 63;
  int wr = w >> 1, wc = w & 1;
  __shared__ __align__(16) u16 smem[2 * 8192];
  u16* As = smem;
  u16* Bs = smem + 8192;
  f32x4 acc1[4][4] = {};
  for (int k0 = 0; k0 < Kg; k0 += 2) {
    __syncthreads();
    #pragma unroll
    for (int i = 0; i < 4; i++) {
      int f = w + 4*i;
      int r = f >> 1, c = f & 1;
      size_t goff = (((size_t)(mg0 + r)) * Kg + (k0 + c)) * 512 + (lane << 3);
      gl_lds16(Ap + goff, &As[f * 512]);
      int cb = f >> 3, tn = f & 7;
      size_t boff = (((size_t)(k0 + cb)) * Ng + (ng0 + tn)) * 512 + (lane << 3);
      gl_lds16(Bp + boff, &Bs[f * 512]);
    }
    __syncthreads();
    #pragma unroll
    for (int kk = 0; kk < 2; kk++) {
      short8v bq[4], av[4];
      #pragma unroll
      for (int j = 0; j < 4; j++)
        bq[j] = *(const short8v*)&Bs[(kk*8 + wc*4 + j)*512 + (lane << 3)];
      #pragma unroll
      for (int i = 0; i < 4; i++)
        av[i] = *(const short8v*)&As[((wr*4 + i)*2 + kk)*512 + (lane << 3)];
      #pragma unroll
      for (int i = 0; i < 4; i++)
        #pragma unroll
        for (int j = 0; j < 4; j++)
          acc1[i][j] = __builtin_amdgcn_mfma_f32_16x16x32_bf16(av[i], bq[j], acc1[i][j], 0, 0, 0);
    }
  }
  #pragma unroll
  for (int i = 0; i < 4; i++) {
    int row = (mg0 + wr*4 + i)*16 + ((lane >> 4) << 2);
    #pragma unroll
    for (int j = 0; j < 4; j++) {
      int col = (ng0 + wc*4 + j)*16 + (lane & 15);
      #pragma unroll
      for (int r = 0; r < 4; r++)
        D[(size_t)(row + r)*N_ + col] =
            f2bf(2.f*acc1[i][j][r] - ((row + r) == col ? 1.f : 0.f));
    }
  }
}

// ---------------- logits GEMM: 8-wave 128x256, 2-buf counted-vmcnt, bf16 out, colmax ----------------
__global__ __launch_bounds__(512) void k_logits(
    const u16* __restrict__ Ap, const u16* __restrict__ Bp,
    u16* __restrict__ lgb, unsigned* __restrict__ cmg) {
  int hw = blockIdx.x + (blockIdx.y << 2) + (blockIdx.z << 5);   // grid (4,8,16)
  int logical = (hw & 7)*64 + (hw >> 3);                         // bijective (512%8==0)
  int ng0 = (logical & 3) * 16;
  int mg0 = ((logical >> 2) & 7) * 8;
  int b   = logical >> 5;
  const u16* A1 = Ap;
  const u16* Bm = Bp + ((size_t)b << 20);
  constexpr int Kg = 32, Ng = 64;
  int tid = threadIdx.x;
  int w = tid >> 6, lane = tid & 63;
  int r2 = w >> 2, c4 = w & 3;
  int lm = lane & 15, hi = lane >> 4;
  __shared__ __align__(16) u16 smem[2 * 12288];
  f32x4 acc[4][4] = {};
  #define LG_STAGE(kg, buf) {                                                   \
    u16* dst = smem + (buf)*12288;                                              \
    size_t goffA = (((size_t)(mg0 + w)) * Kg + (kg)) * 512 + (lane << 3);       \
    gl_lds16(A1 + goffA, &dst[w*512]);                                          \
    size_t bo0 = (((size_t)(kg)) * Ng + (ng0 + w)) * 512 + (lane << 3);         \
    gl_lds16(Bm + bo0, &dst[4096 + w*512]);                                     \
    size_t bo1 = (((size_t)(kg)) * Ng + (ng0 + w + 8)) * 512 + (lane << 3);     \
    gl_lds16(Bm + bo1, &dst[4096 + (w + 8)*512]);                               \
  }
  LG_STAGE(0, 0);
  for (int kg = 0; kg < Kg; kg++) {
    int cur = kg & 1;
    if (kg + 1 < Kg) {
      LG_STAGE(kg + 1, cur ^ 1);
      asm volatile("s_waitcnt vmcnt(3)" ::: "memory");   // cur's 3 loads done; next's 3 in flight
    } else {
      asm volatile("s_waitcnt vmcnt(0)" ::: "memory");
    }
    __builtin_amdgcn_s_barrier();
    __builtin_amdgcn_sched_barrier(0);
    const u16* Asrc = smem + cur*12288;
    const u16* Bsrc = Asrc + 4096;
    short8v bq[4];
    #pragma unroll
    for (int j = 0; j < 4; j++)
      bq[j] = *(const short8v*)&Bsrc[(c4*4 + j)*512 + (lane << 3)];
    __builtin_amdgcn_s_setprio(1);
    #pragma unroll
    for (int i = 0; i < 4; i++) {
      short8v av = *(const short8v*)&Asrc[(r2*4 + i)*512 + (lane << 3)];
      #pragma unroll
      for (int j = 0; j < 4; j++)
        acc[i][j] = __builtin_amdgcn_mfma_f32_16x16x32_bf16(av, bq[j], acc[i][j], 0, 0, 0);
    }
    __builtin_amdgcn_s_setprio(0);
    asm volatile("" ::: "memory");
    __builtin_amdgcn_s_barrier();
  }
  #undef LG_STAGE
  __shared__ unsigned cmL[256];
  if (tid < 256) cmL[tid] = 0u;
  __syncthreads();
  #pragma unroll
  for (int j = 0; j < 4; j++) {
    float m = -3.4e38f;
    #pragma unroll
    for (int i = 0; i < 4; i++)
      #pragma unroll
      for (int r = 0; r < 4; r++) m = fmaxf(m, acc[i][j][r]);
    m = fmaxf(m, __shfl_xor(m, 16));
    m = fmaxf(m, __shfl_xor(m, 32));
    if (hi == 0)
      atomicMax(&cmL[(c4*4 + j)*16 + lm], fkey(m));
  }
  __syncthreads();
  if (tid < 256)
    atomicMax(&cmg[(size_t)b*N_ + ng0*16 + tid], cmL[tid]);
  u16* d1 = lgb + ((size_t)b << 20);
  #pragma unroll
  for (int i = 0; i < 4; i++) {
    int row = (mg0 + r2*4 + i)*16 + (hi << 2);
    #pragma unroll
    for (int j = 0; j < 4; j++) {
      int col = (ng0 + c4*4 + j)*16 + lm;
      #pragma unroll
      for (int r = 0; r < 4; r++)
        d1[(size_t)(row + r)*N_ + col] = f2bf(acc[i][j][r]);
    }
  }
}

// ---------------- fused: row softmax + S_coef + A1/A2 pack (bf16 sup reads) + pad ----------------
__global__ __launch_bounds__(256) void k_smpk(const u16* __restrict__ lgb,
    float* __restrict__ Sout, const unsigned* __restrict__ cm,
    const u16* __restrict__ supR, const u16* __restrict__ sup2B,
    u16* __restrict__ A1p, u16* __restrict__ A2p, u16* __restrict__ gcnB) {
  int bm = blockIdx.x;                               // b*1024 + row
  int b = bm >> 10, row = bm & 1023;
  int t = threadIdx.x;
  int k0 = t * 4;
  const unsigned* cmb = cm + (size_t)b * N_;
  short4v l4 = *(const short4v*)&lgb[(size_t)bm * N_ + k0];
  float v[4];
  #pragma unroll
  for (int j = 0; j < 4; j++) v[j] = bf2f((u16)l4[j]) - funkey(cmb[k0 + j]);
  float mx = fmaxf(fmaxf(v[0], v[1]), fmaxf(v[2], v[3]));
  #pragma unroll
  for (int off = 32; off; off >>= 1) mx = fmaxf(mx, __shfl_down(mx, off));
  __shared__ float sm[4], ss[4];
  int w = t >> 6, lane = t & 63;
  if (lane == 0) sm[w] = mx;
  __syncthreads();
  mx = fmaxf(fmaxf(sm[0], sm[1]), fmaxf(sm[2], sm[3]));
  float e[4]; float s = 0.f;
  #pragma unroll
  for (int j = 0; j < 4; j++) { e[j] = expf(v[j] - mx); s += e[j]; }
  #pragma unroll
  for (int off = 32; off; off >>= 1) s += __shfl_down(s, off);
  if (lane == 0) ss[w] = s;
  __syncthreads();
  float inv = 1.f / (ss[0] + ss[1] + ss[2] + ss[3]);
  float p[4];
  #pragma unroll
  for (int j = 0; j < 4; j++) p[j] = e[j] * inv;
  *(float4*)&Sout[(size_t)bm * N_ + k0] = make_float4(p[0], p[1], p[2], p[3]);
  short4v s1v = *(const short4v*)&supR[(size_t)row*N_ + k0];
  short4v s2v = *(const short4v*)&sup2B[(size_t)row*N_ + k0];
  unsigned fi = (unsigned)((row >> 4) << 5) | (unsigned)(k0 >> 5);
  unsigned lp = (unsigned)(row & 15) | ((unsigned)((k0 >> 3) & 3) << 4);
  size_t dst = ((size_t)b << 20) + ((size_t)fi << 9) + (lp << 3) + (k0 & 7);
  u16 o1[4], o2[4];
  #pragma unroll
  for (int j = 0; j < 4; j++) {
    o1[j] = f2bf(p[j] * bf2f((u16)s1v[j]));
    o2[j] = f2bf(p[j] * bf2f((u16)s2v[j]));
  }
  *(unsigned long long*)&A1p[dst] = *(unsigned long long*)o1;
  *(unsigned long long*)&A2p[dst] = *(unsigned long long*)o2;
  if (t < 32) {
    size_t po = ((size_t)bm*26 + (t >> 4)*25)*64 + (t & 15)*4;
    *(unsigned long long*)&gcnB[po] = 0ull;
  }
}

// ---------------- x_TAt: 8-node blocks, reads bf16 xr, coalesced writes ----------------
__global__ __launch_bounds__(768) void k_xtat8(const u16* __restrict__ xr,
    const float* __restrict__ Tout, u16* __restrict__ xTlc,
    u16* __restrict__ Xp) {
  int blk = blockIdx.x;                              // B*128
  int b = blk >> 7, n0 = (blk & 127) << 3;
  __shared__ float xs[6400];                         // [nl][c*25 + l]
  __shared__ float Tl[576];
  int tid = threadIdx.x;
  const u16* xrb = xr + (size_t)(b*N_ + n0)*768;
  #pragma unroll
  for (int nl = 0; nl < 8; nl++) {
    u16 v = xrb[(size_t)nl*768 + tid];
    int l = tid >> 5, c = tid & 31;
    xs[nl*800 + c*25 + l] = bf2f(v);
  }
  if (tid < 576) Tl[tid] = Tout[(size_t)b*576 + tid];
  __syncthreads();
  int q = tid >> 5, cc = tid & 31;
  u16 xp8[8];
  #pragma unroll
  for (int nl = 0; nl < 8; nl++) {
    const float* xsn = &xs[nl*800 + cc*25];
    float acc = 0.f;
    #pragma unroll
    for (int ll = 0; ll < 24; ll++) acc += xsn[ll] * Tl[ll*24 + q];
    u16 bv = f2bf(acc);
    size_t bn = (size_t)b*N_ + n0 + nl;
    xTlc[bn*768 + tid] = bv;
    xp8[nl] = bv;
  }
  int fi = (n0 >> 5)*48 + (tid >> 4);
  int lidx = (tid & 15) | (((n0 >> 3) & 3) << 4);
  *(short8v*)&Xp[(size_t)b*786432 + (size_t)fi*512 + lidx*8] = *(short8v*)xp8;
}

// ---------------- fused Chebyshev dual GEMM + GA — 8-wave, 2-buf counted-vmcnt ----------------
__global__ __launch_bounds__(512) void k_chga(
    const u16* __restrict__ A1p, const u16* __restrict__ A2p,
    const u16* __restrict__ Bp, const u16* __restrict__ xTlc,
    const float* __restrict__ S, const u16* __restrict__ WAp,
    const float* __restrict__ gcn_b, u16* __restrict__ gcn) {
  int hw = blockIdx.x + 6*blockIdx.y + 48*blockIdx.z;  // grid (6,8,16)
  int logical = (hw & 7)*96 + (hw >> 3);               // bijective
  int tx = logical % 6; int tmp = logical / 6;
  int ty = tmp & 7; int b = tmp >> 3;
  const u16* A1 = A1p + ((size_t)b << 20);
  const u16* A2 = A2p + ((size_t)b << 20);
  const u16* Bm = Bp + (size_t)b * 786432;
  int mg0 = ty * 8;
  int ng0 = tx * 8;
  int l0 = tx * 4;
  constexpr int Kg = 32, Ng = 48;
  int tid = threadIdx.x;
  int w = tid >> 6, lane = tid & 63;
  int m  = w & 1;
  int c2 = (w >> 1) & 1;
  int r2 = w >> 2;
  int lm = lane & 15, hi = lane >> 4;
  __shared__ __align__(16) u16 smem[2 * 12288];
  f32x4 acc[4][4] = {};
  #define CH_STAGE(kg, buf) {                                                   \
    u16* dst = smem + (buf)*12288;                                              \
    size_t goffA = (((size_t)(mg0 + w)) * Kg + (kg)) * 512 + (lane << 3);       \
    gl_lds16(A1 + goffA, &dst[w*512]);                                          \
    gl_lds16(A2 + goffA, &dst[4096 + w*512]);                                   \
    size_t bo = (((size_t)(kg)) * Ng + (ng0 + w)) * 512 + (lane << 3);          \
    gl_lds16(Bm + bo, &dst[8192 + w*512]);                                      \
  }
  CH_STAGE(0, 0);
  for (int kg = 0; kg < Kg; kg++) {
    int cur = kg & 1;
    if (kg + 1 < Kg) {
      CH_STAGE(kg + 1, cur ^ 1);
      asm volatile("s_waitcnt vmcnt(3)" ::: "memory");   // cur's 3 loads done; next's 3 in flight
    } else {
      asm volatile("s_waitcnt vmcnt(0)" ::: "memory");
    }
    __builtin_amdgcn_s_barrier();
    __builtin_amdgcn_sched_barrier(0);
    const u16* base = smem + cur*12288;
    const u16* Asrc = base + (m ? 4096 : 0);
    const u16* Bsrc = base + 8192;
    short8v bq[4];
    #pragma unroll
    for (int j = 0; j < 4; j++)
      bq[j] = *(const short8v*)&Bsrc[(c2*4 + j)*512 + (lane << 3)];
    __builtin_amdgcn_s_setprio(1);
    #pragma unroll
    for (int i = 0; i < 4; i++) {
      short8v av = *(const short8v*)&Asrc[(r2*4 + i)*512 + (lane << 3)];
      #pragma unroll
      for (int j = 0; j < 4; j++)
        acc[i][j] = __builtin_amdgcn_mfma_f32_16x16x32_bf16(av, bq[j], acc[i][j], 0, 0, 0);
    }
    __builtin_amdgcn_s_setprio(0);
    asm volatile("" ::: "memory");
    __builtin_amdgcn_s_barrier();
  }
  #undef CH_STAGE
  // ---- GA phase ----
  u16* zL  = smem;                           // z1 [0,9216), z2 [9216,18432)
  u16* wsm = smem + 18432;                   // GA weights, 6144 u16
  float gb[4];
  #pragma unroll
  for (int cf = 0; cf < 4; cf++) gb[cf] = gcn_b[cf*16 + lm];
  #pragma unroll
  for (int ch = 0; ch < 2; ch++) {
    __syncthreads();
    if (ch == 0) {
      gl_lds16(WAp + w*512 + (lane << 3), &wsm[w*512 + (lane << 3)]);
      if (w < 4)
        gl_lds16(WAp + (8 + w)*512 + (lane << 3), &wsm[(8 + w)*512 + (lane << 3)]);
    }
    if (r2 == ch) {
      #pragma unroll
      for (int i = 0; i < 4; i++)
        #pragma unroll
        for (int j = 0; j < 4; j++) {
          int col = (c2*4 + j)*16 + lm;
          int ll = col >> 5, c = col & 31;
          #pragma unroll
          for (int r = 0; r < 4; r++) {
            int lr = (i*16 + hi*4 + r)*4 + ll;
            int za = lr*36 + ((((c >> 3) + (lr >> 4)) & 3) << 3) + (c & 7);
            zL[m*9216 + za] = f2bf(acc[i][j][r]);
          }
        }
    }
    __syncthreads();
    #pragma unroll
    for (int gg = 0; gg < 2; gg++) {
      int g = w*2 + gg;
      int lr = g*16 + lm;
      int grow = ch*256 + lr;
      int nl = mg0*16 + (grow >> 2);
      int ll = l0 + (grow & 3);
      short8v a0 = *(const short8v*)&xTlc[(size_t)b*786432 + ((size_t)nl*24 + ll)*32 + hi*8];
      float sd = S[((size_t)b << 20) + (size_t)nl*1025];
      #pragma unroll
      for (int jj = 0; jj < 8; jj++)
        a0[jj] = (short)f2bf(bf2f((u16)a0[jj]) * sd);
      int slot = (hi + g) & 3;
      const u16* zp = &zL[lr*36 + slot*8];
      short4v z1lo = *(const short4v*)zp;
      short4v z1hi = *(const short4v*)(zp + 4);
      short4v z2lo = *(const short4v*)(zp + 9216);
      short4v z2hi = *(const short4v*)(zp + 9220);
      short8v a1 = {z1lo[0], z1lo[1], z1lo[2], z1lo[3], z1hi[0], z1hi[1], z1hi[2], z1hi[3]};
      short8v a2 = {z2lo[0], z2lo[1], z2lo[2], z2lo[3], z2hi[0], z2hi[1], z2hi[2], z2hi[3]};
      #pragma unroll
      for (int cf = 0; cf < 4; cf++) {
        short8v w0 = *(const short8v*)&wsm[(0*4 + cf)*512 + (lane << 3)];
        short8v w1 = *(const short8v*)&wsm[(1*4 + cf)*512 + (lane << 3)];
        short8v w2 = *(const short8v*)&wsm[(2*4 + cf)*512 + (lane << 3)];
        f32x4 a = {};
        a = __builtin_amdgcn_mfma_f32_16x16x32_bf16(a0, w0, a, 0, 0, 0);
        a = __builtin_amdgcn_mfma_f32_16x16x32_bf16(a1, w1, a, 0, 0, 0);
        a = __builtin_amdgcn_mfma_f32_16x16x32_bf16(a2, w2, a, 0, 0, 0);
        int o = cf*16 + lm;
        #pragma unroll
        for (int r = 0; r < 4; r++) {
          int gr2 = ch*256 + g*16 + hi*4 + r;
          int n2 = mg0*16 + (gr2 >> 2);
          int l2 = l0 + (gr2 & 3);
          gcn[(((size_t)b*1024 + n2)*26 + l2 + 1)*64 + o] =
              f2bf(fmaxf(a[r] + gb[cf], 0.f));
        }
      }
    }
  }
}

// ---------------- GB: pre -> bf16 staging + LN partials ----------------
__global__ __launch_bounds__(256) void k_gb(const u16* __restrict__ gcn,
    const u16* __restrict__ xr, const u16* __restrict__ W2p,
    const float* __restrict__ time_b, const float* __restrict__ conv1_b,
    u16* __restrict__ preB, float* __restrict__ partials) {
  int blk = blockIdx.x;
  int b = blk / 192, mt = blk % 192;
  int tid = threadIdx.x, w = tid >> 6, lane = tid & 63;
  int lm = lane & 15, hi = lane >> 4;
  f32x4 acc[2][4] = {};
  #pragma unroll
  for (int g = 0; g < 7; g++) {
    short8v Bf[4];
    #pragma unroll
    for (int cf = 0; cf < 4; cf++)
      Bf[cf] = *(const short8v*)&W2p[(g*4 + cf)*512 + lane*8];
    #pragma unroll
    for (int rf = 0; rf < 2; rf++) {
      int row = mt*128 + (w*2 + rf)*16 + lm;
      short8v a;
      if (g < 6) {
        int n = row / 24, l = row - 24*n;
        int ts = g >> 1, o0 = (g & 1)*32;
        a = *(const short8v*)&gcn[(((size_t)b*1024 + n)*26 + l + ts)*64 + o0 + hi*8];
      } else {
        a = *(const short8v*)&xr[(size_t)b*786432 + (size_t)row*32 + hi*8];
      }
      #pragma unroll
      for (int cf = 0; cf < 4; cf++)
        acc[rf][cf] = __builtin_amdgcn_mfma_f32_16x16x32_bf16(a, Bf[cf], acc[rf][cf], 0, 0, 0);
    }
  }
  float s1 = 0.f, s2 = 0.f;
  #pragma unroll
  for (int rf = 0; rf < 2; rf++) {
    int rbase = mt*128 + (w*2 + rf)*16 + hi*4;
    int n = rbase / 24, l0 = rbase - 24*n;
    #pragma unroll
    for (int cf = 0; cf < 4; cf++) {
      int o2 = cf*16 + lm;
      float bias = time_b[o2] + conv1_b[o2];
      u16 ov[4];
      #pragma unroll
      for (int r = 0; r < 4; r++) {
        float pre = fmaxf(acc[rf][cf][r] + bias, 0.f);
        s1 += pre; s2 += pre*pre; ov[r] = f2bf(pre);
      }
      *(unsigned long long*)&preB[(((size_t)b*64 + o2)*1024 + n)*24 + l0] =
          *(unsigned long long*)ov;
    }
  }
  #pragma unroll
  for (int off = 32; off; off >>= 1) { s1 += __shfl_down(s1, off); s2 += __shfl_down(s2, off); }
  __shared__ float red[8];
  if (lane == 0) { red[w*2] = s1; red[w*2 + 1] = s2; }
  __syncthreads();
  if (tid == 0) {
    float t1 = 0.f, t2 = 0.f;
    for (int ww = 0; ww < 4; ww++) { t1 += red[ww*2]; t2 += red[ww*2 + 1]; }
    partials[blk*2] = t1; partials[blk*2 + 1] = t2;
  }
}

__global__ __launch_bounds__(256) void k_bstats(const float* __restrict__ partials,
                                                float* __restrict__ bstats) {
  int b = blockIdx.x; int tid = threadIdx.x;
  __shared__ float r1[256], r2[256];
  r1[tid] = (tid < 192) ? partials[(b*192 + tid)*2] : 0.f;
  r2[tid] = (tid < 192) ? partials[(b*192 + tid)*2 + 1] : 0.f;
  __syncthreads();
  for (int off = 128; off; off >>= 1) {
    if (tid < off) { r1[tid] += r1[tid + off]; r2[tid] += r2[tid + off]; }
    __syncthreads();
  }
  if (tid == 0) { bstats[b*2] = r1[0]; bstats[b*2 + 1] = r2[0]; }
}

__global__ void k_ln4(const u16* __restrict__ preB, float4* __restrict__ out,
                      const float* __restrict__ bstats,
                      const float4* __restrict__ lnw, const float4* __restrict__ lnb) {
  constexpr size_t PER4 = (size_t)CO_*N_*L_/4;
  size_t i = (size_t)blockIdx.x * 256 + threadIdx.x;
  int b = (int)(i / PER4); size_t r = i % PER4;
  float cnt = (float)(PER4*4);
  float mu = bstats[b*2] / cnt;
  float var = bstats[b*2 + 1] / cnt - mu*mu;
  float inv = rsqrtf(var + 1e-5f);
  short4v p4 = *(const short4v*)&preB[i*4];
  float4 w = lnw[r], bb = lnb[r];
  float4 o;
  o.x = (bf2f((u16)p4[0]) - mu)*inv*w.x + bb.x;
  o.y = (bf2f((u16)p4[1]) - mu)*inv*w.y + bb.y;
  o.z = (bf2f((u16)p4[2]) - mu)*inv*w.z + bb.z;
  o.w = (bf2f((u16)p4[3]) - mu)*inv*w.w + bb.w;
  out[i] = o;
}
} // namespace

extern "C" void kernel_launch(void* const* d_in, const int* in_sizes, int n_in,
                              void* d_out, int out_size, void* d_ws, size_t ws_size,
                              hipStream_t stream) {
  const float* x        = (const float*)d_in[0];
  const float* supports = (const float*)d_in[1];
  const float* conv1_w  = (const float*)d_in[2];
  const float* conv1_b  = (const float*)d_in[3];
  const float* t1w      = (const float*)d_in[4];
  const float* t2w      = (const float*)d_in[5];
  const float* t_w      = (const float*)d_in[6];
  const float* t_b      = (const float*)d_in[7];
  const float* t_v      = (const float*)d_in[8];
  const float* s1w      = (const float*)d_in[9];
  const float* s2w      = (const float*)d_in[10];
  const float* s_w      = (const float*)d_in[11];
  const float* s_b      = (const float*)d_in[12];
  const float* s_v      = (const float*)d_in[13];
  const float* gcn_w    = (const float*)d_in[14];
  const float* gcn_b    = (const float*)d_in[15];
  const float* time_w   = (const float*)d_in[16];
  const float* time_b   = (const float*)d_in[17];
  const float* ln_w     = (const float*)d_in[18];
  const float* ln_b     = (const float*)d_in[19];

  float* out  = (float*)d_out;
  float* Sout = out + S_OFF;
  float* Tout = out + T_OFF;
  u16*   outU = (u16*)d_out;
  float* ws   = (float*)d_ws;

  u16*   gcnB = (u16*)(ws + O_GCN);
  u16*   rawp = (u16*)(ws + O_GCN);      // alias: dead before gcnB written
  u16*   xTlc = (u16*)(ws + O_XTLC);
  u16*   xr   = (u16*)(ws + O_XR);
  u16*   supB = (u16*)(ws + O_SUPB);
  u16*   lgb  = (u16*)(ws + O_LGB);
  float* part2= ws + O_LGB;              // alias: consumed before lgb written
  u16*   preB = (u16*)(ws + O_LGB);      // alias: lgb/f1t dead before k_gb writes
  float* f1t  = ws + O_F1T;
  float* f2t  = ws + O_F2T;
  u16*   f2p  = (u16*)(ws + O_F2S);
  float* g_t  = ws + O_GT;
  u16*   gsp  = (u16*)(ws + O_GS);
  unsigned* cm = (unsigned*)(ws + O_CM);
  u16*   WAp  = (u16*)(ws + O_WAP);
  u16*   W2p  = (u16*)(ws + O_W2P);
  float* part = ws + O_PART;
  float* bst  = ws + O_BST;

  u16*   A1p  = outU + OS_A1;
  u16*   A2p  = outU + OS_A2;
  u16*   Xp   = outU + OS_XP;
  u16*   svp  = outU + OS_SV;
  u16*   sup2B= outU + OS_SUP2;
  u16*   supR = outU + OS_SUPR;
  u16*   supA = outU + OS_SUPA;

  k_ff<<<2048, 256, 0, stream>>>(x, t1w, s1w, s2w, t2w, s_w, f1t, gsp, f2p, part2, xr);
  k_aux<<<432, 256, 0, stream>>>(part2, f2t, f1t, t_w, g_t);
  k_tatt<<<B_, 576, 0, stream>>>(g_t, f2t, t_b, t_v, Tout);
  k_rawsm<<<dim3(8, 8, B_), 256, 0, stream>>>(gsp, f2p, s_b, rawp);
  k_pack_sv<<<512, 256, 0, stream>>>(s_v, svp, supports, supA, supB, supR,
                                     gcn_w, time_w, conv1_w, WAp, W2p, cm);
  k_sup2<<<dim3(8, 8), 256, 0, stream>>>(supA, supB, sup2B);
  k_logits<<<dim3(4, 8, B_), 512, 0, stream>>>(svp, rawp, lgb, cm);
  k_smpk<<<B_*N_, 256, 0, stream>>>(lgb, Sout, cm, supR, sup2B, A1p, A2p, gcnB);
  k_xtat8<<<2048, 768, 0, stream>>>(xr, Tout, xTlc, Xp);
  k_chga<<<dim3(6, 8, B_), 512, 0, stream>>>(A1p, A2p, Xp, xTlc, Sout, WAp, gcn_b, gcnB);
  k_gb<<<3072, 256, 0, stream>>>(gcnB, xr, W2p, time_b, conv1_b, preB, part);
  k_bstats<<<B_, 256, 0, stream>>>(part, bst);
  k_ln4<<<24576, 256, 0, stream>>>(preB, (float4*)out, bst,
                                   (const float4*)ln_w, (const float4*)ln_b);
}

// Round 20
// 367.275 us; speedup vs baseline: 1.0121x; 1.0121x over previous
//
#include <hip/hip_runtime.h>
#include <cstddef>

namespace {
constexpr int B_ = 16, C_ = 32, N_ = 1024, L_ = 24, CO_ = 64;

constexpr size_t S_OFF = (size_t)B_*CO_*N_*L_;            // 25165824 floats
constexpr size_t T_OFF = S_OFF + (size_t)B_*N_*N_;        // 41943040

// ---- workspace layout (f32 units) ----
constexpr size_t O_GCN  = 0;                              // gcn bf16 [B][N][26][64] (rawp aliases)
constexpr size_t O_XTLC = 13631488;                       // xT bf16 [B][N][24][32]
constexpr size_t O_XR   = 19922944;                       // x  bf16 [B][N][24][32]
constexpr size_t O_SUPB = 26214400;                       // supB packed bf16 (1M u16)
constexpr size_t O_LGB  = 26738688;                       // logits bf16 / part2 (early) / preB bf16 (late)
constexpr size_t O_F1T  = 38797312;
constexpr size_t O_F2T  = 39583744;
constexpr size_t O_F2S  = 39596032;                       // f2p packed bf16 (512K u16)
constexpr size_t O_GT   = 40120320;
constexpr size_t O_GS   = 40132608;                       // gsp packed bf16 (512K u16)
constexpr size_t O_CM   = 40656896;                       // colmax keys u32 [B][N]
constexpr size_t O_WAP  = 40673280;                       // GA weights packed (6144 u16)
constexpr size_t O_W2P  = 40676352;                       // GB weights packed (14336 u16)
constexpr size_t O_PART = 40683520;                       // [3072][2]
constexpr size_t O_BST  = 40689664;                       // [B][2]

// ---- d_out scratch (u16 units), region [0, S_OFF floats) dead until k_gb ----
constexpr size_t OS_A1  = 0;
constexpr size_t OS_A2  = OS_A1 + (size_t)B_*N_*N_;
constexpr size_t OS_XP  = OS_A2 + (size_t)B_*N_*N_;
constexpr size_t OS_SV  = OS_XP + (size_t)B_*N_*768;
constexpr size_t OS_SUP2= OS_SV + (size_t)N_*N_;          // sup2 bf16 row-major (1M u16)
constexpr size_t OS_SUPR= OS_SUP2 + (size_t)N_*N_;        // supports bf16 row-major (1M u16)
constexpr size_t OS_SUPA= OS_SUPR + (size_t)N_*N_;        // supA packed bf16 (1M u16)

typedef unsigned short u16;
typedef __attribute__((ext_vector_type(8))) short short8v;
typedef __attribute__((ext_vector_type(4))) short short4v;
typedef __attribute__((ext_vector_type(4))) float f32x4;

__device__ __forceinline__ u16 f2bf(float x) {
  unsigned u = __builtin_bit_cast(unsigned, x);
  return (u16)((u + 0x7fffu + ((u >> 16) & 1u)) >> 16);
}
__device__ __forceinline__ float bf2f(u16 v) {
  return __builtin_bit_cast(float, ((unsigned)v) << 16);
}
// monotonic float<->unsigned key (order-preserving; max on keys == max on floats)
__device__ __forceinline__ unsigned fkey(float f) {
  unsigned u = __builtin_bit_cast(unsigned, f);
  return (u & 0x80000000u) ? ~u : (u | 0x80000000u);
}
__device__ __forceinline__ float funkey(unsigned k) {
  unsigned u = (k & 0x80000000u) ? (k ^ 0x80000000u) : ~k;
  return __builtin_bit_cast(float, u);
}
__device__ __forceinline__ void gl_lds16(const void* g, void* l) {
  __builtin_amdgcn_global_load_lds(
      (const __attribute__((address_space(1))) unsigned int*)g,
      (__attribute__((address_space(3))) unsigned int*)l, 16, 0, 0);
}

// ---------------- fused stage 1: f1t + gsp + f2p + f2t partials + xr, one x pass ----------------
__global__ __launch_bounds__(256) void k_ff(const float* __restrict__ x,
    const float* __restrict__ t1w, const float* __restrict__ s1w,
    const float* __restrict__ w2s, const float* __restrict__ t2w,
    const float* __restrict__ sw, float* __restrict__ f1t,
    u16* __restrict__ gsp, u16* __restrict__ f2p,
    float* __restrict__ part2, u16* __restrict__ xr) {
  int blk = blockIdx.x;                              // B*128
  int b = blk >> 7, n0 = (blk & 127) << 3;
  __shared__ float ls[32*200];                       // [c][nl*25 + l], stride-25 pad
  __shared__ float tls[8*33];
  __shared__ float f1sL[200];                        // [nl*25 + l]
  int t = threadIdx.x;
  const float* xb = x + (size_t)b*C_*N_*L_;
  #pragma unroll
  for (int i = 0; i < 24; i++) {
    int flat = i*256 + t;
    int c = flat / 192, r = flat - c*192;
    int nl = r / 24, l = r - nl*24;
    ls[c*200 + nl*25 + l] = xb[((size_t)c*N_ + n0 + nl)*L_ + l];
  }
  __syncthreads();
  if (t < 192) {
    int nl = t / 24, l = t - (t/24)*24;
    float a1 = 0.f, a2 = 0.f;
    #pragma unroll
    for (int c = 0; c < C_; c++) {
      float v = ls[c*200 + nl*25 + l];
      a1 += v * t1w[c]; a2 += v * s1w[c];
    }
    f1t[((size_t)b*L_ + l)*N_ + n0 + nl] = a1;
    f1sL[nl*25 + l] = a2;
  }
  {
    int c = t >> 3, nl = t & 7;
    const float* lp = &ls[c*200 + nl*25];
    float a = 0.f;
    #pragma unroll
    for (int l = 0; l < L_; l++) a += lp[l] * w2s[l];
    tls[nl*33 + c] = a;
  }
  const float* twn = t2w + n0;
  #pragma unroll
  for (int i = 0; i < 3; i++) {
    int flat = t + 256*i;
    int c2 = flat / 24, l2 = flat - c2*24;
    float a2 = 0.f;
    #pragma unroll
    for (int nl2 = 0; nl2 < 8; nl2++)
      a2 += ls[c2*200 + nl2*25 + l2] * twn[nl2];
    part2[(size_t)blk*768 + flat] = a2;
  }
  // xr: bf16 copy of x in [n][l*32+c] order (coalesced 512B/wave writes)
  u16* xrb = xr + (size_t)(b*N_ + n0)*768;
  #pragma unroll
  for (int i = 0; i < 24; i++) {
    int flat = i*256 + t;
    int nl = flat / 768, r = flat - nl*768;
    int l = r >> 5, c = r & 31;
    xrb[flat] = f2bf(ls[c*200 + nl*25 + l]);
  }
  __syncthreads();
  // f2p: B-fragment layout for f2s[c][m]; m = n0 + (t>>5), c = t&31
  {
    int m = n0 + (t >> 5), c = t & 31;
    float v = tls[(t >> 5)*33 + c];
    f2p[(size_t)b*32768 + (size_t)(m >> 4)*512 +
        (((m & 15) | ((c >> 3) << 4)) << 3) + (c & 7)] = f2bf(v);
  }
  // gsp: A-fragment layout for g_s[n][c] = sum_l f1s[n][l]*sw[l*32+c]
  {
    int nl = t >> 5, cg = t & 31;
    const float* fl = &f1sL[nl*25];
    float ag = 0.f;
    #pragma unroll
    for (int l = 0; l < L_; l++) ag += fl[l] * sw[l*32 + cg];
    int n = n0 + nl;
    gsp[(size_t)b*32768 + (size_t)(n >> 4)*512 +
        (((n & 15) | ((cg >> 3) << 4)) << 3) + (cg & 7)] = f2bf(ag);
  }
}

// ---------------- merged: f2t reduce (blocks 0..47) + g_t (blocks 48..431) ----------------
__global__ __launch_bounds__(256) void k_aux(const float* __restrict__ part2,
    float* __restrict__ f2t, const float* __restrict__ f1t,
    const float* __restrict__ tw, float* __restrict__ g_t) {
  int blk = blockIdx.x;
  int t = threadIdx.x;
  if (blk < 48) {
    int idx = blk * 256 + t;                         // B*768 = 12288
    int b = idx / 768, cl = idx - b*768;
    const float* p = part2 + (size_t)b*98304 + cl;
    float s = 0.f;
    #pragma unroll 8
    for (int k = 0; k < 128; k++) s += p[(size_t)k*768];
    f2t[idx] = s;
    return;
  }
  int bl = blk - 48;                                 // 0..383 = B*L
  int nsub = t >> 5, c = t & 31;
  const float* f = f1t + (size_t)bl * N_;
  float a = 0.f;
  for (int i = 0; i < 128; i++) {
    int n = nsub + (i << 3);
    a += f[n] * tw[n*32 + c];
  }
  __shared__ float s[256];
  s[t] = a; __syncthreads();
  if (t < 128) s[t] += s[t + 128];
  __syncthreads();
  if (t < 64) s[t] += s[t + 64];
  __syncthreads();
  if (t < 32) g_t[(size_t)bl*32 + t] = s[t] + s[t + 32];
}

// ---------------- temporal attention ----------------
__global__ __launch_bounds__(576) void k_tatt(const float* __restrict__ g_t,
    const float* __restrict__ f2t, const float* __restrict__ tb,
    const float* __restrict__ tv, float* __restrict__ Tout) {
  int b = blockIdx.x; int tid = threadIdx.x;
  int l = tid / 24, q = tid % 24;
  __shared__ float rawS[576], logS[576], cmS[24], rmS[24], rsS[24];
  float acc = tb[tid];
  const float* g = g_t + ((size_t)b*L_ + l)*C_;
  const float* f = f2t + (size_t)b*C_*L_ + q;
  #pragma unroll
  for (int c = 0; c < C_; c++) acc += g[c] * f[(size_t)c*L_];
  rawS[tid] = 1.f / (1.f + expf(-acc));
  __syncthreads();
  float lg = 0.f;
  #pragma unroll
  for (int k = 0; k < L_; k++) lg += tv[l*L_ + k] * rawS[k*L_ + q];
  logS[tid] = lg;
  __syncthreads();
  if (l == 0) { float m = -3.4e38f; for (int mm = 0; mm < L_; mm++) m = fmaxf(m, logS[mm*L_ + q]); cmS[q] = m; }
  __syncthreads();
  float lc = lg - cmS[q];
  logS[tid] = lc;
  __syncthreads();
  if (q == 0) { float m = -3.4e38f; for (int qq = 0; qq < L_; qq++) m = fmaxf(m, logS[l*L_ + qq]); rmS[l] = m; }
  __syncthreads();
  float e = expf(lc - rmS[l]);
  logS[tid] = e;
  __syncthreads();
  if (q == 0) { float s = 0.f; for (int qq = 0; qq < L_; qq++) s += logS[l*L_ + qq]; rsS[l] = s; }
  __syncthreads();
  Tout[(size_t)b*576 + q*24 + l] = e / rsS[l];
}

// ---------------- merged: raw_s MFMA (z<16) + sup2 GEMM (z==16) ----------------
__global__ __launch_bounds__(256) void k_rsup(
    const u16* __restrict__ gsp, const u16* __restrict__ f2p,
    const float* __restrict__ sb, u16* __restrict__ rawp,
    const u16* __restrict__ supA, const u16* __restrict__ supB,
    u16* __restrict__ sup2D) {
  int tid = threadIdx.x;
  int w = tid >> 6, lane = tid & 63;
  int wr = w >> 1, wc = w & 1;
  int lm = lane & 15, hi = lane >> 4;
  __shared__ __align__(16) u16 smem[2 * 8192];
  if (blockIdx.z < 16) {
    // ---- rawsm path ----
    int b = blockIdx.z;
    int mg0 = blockIdx.y * 8;                        // n 16-groups
    int ng0 = blockIdx.x * 8;                        // m 16-groups
    const u16* A  = gsp + (size_t)b*32768;
    const u16* Bm = f2p + (size_t)b*32768;
    #pragma unroll
    for (int i = 0; i < 4; i++) {
      int f = w + 4*i;
      if (f < 8)
        gl_lds16(A + (size_t)(mg0 + f)*512 + (lane << 3), &smem[f*512]);
      else
        gl_lds16(Bm + (size_t)(ng0 + f - 8)*512 + (lane << 3), &smem[f*512]);
    }
    __syncthreads();
    f32x4 acc[4][4] = {};
    #pragma unroll
    for (int j = 0; j < 4; j++) {
      short8v bv = *(const short8v*)&smem[(8 + wc*4 + j)*512 + (lane << 3)];
      #pragma unroll
      for (int i = 0; i < 4; i++) {
        short8v av = *(const short8v*)&smem[(wr*4 + i)*512 + (lane << 3)];
        acc[i][j] = __builtin_amdgcn_mfma_f32_16x16x32_bf16(av, bv, acc[i][j], 0, 0, 0);
      }
    }
    u16* d = rawp + ((size_t)b << 20);
    #pragma unroll
    for (int i = 0; i < 4; i++) {
      int nb = (mg0 + wr*4 + i)*16 + hi*4;           // base row (k-dim of rawp)
      #pragma unroll
      for (int j = 0; j < 4; j++) {
        int m = (ng0 + wc*4 + j)*16 + lm;            // column
        const float* sbp = sb + (size_t)nb*N_ + m;
        u16 ov[4];
        #pragma unroll
        for (int r = 0; r < 4; r++) {
          float v2 = acc[i][j][r] + sbp[(size_t)r*N_];
          ov[r] = f2bf(1.f / (1.f + expf(-v2)));
        }
        int fi2 = ((nb >> 5) << 6) | (m >> 4);
        int lp  = (m & 15) | (((nb >> 3) & 3) << 4);
        *(unsigned long long*)&d[(size_t)fi2*512 + lp*8 + (nb & 7)] =
            *(unsigned long long*)ov;
      }
    }
    return;
  }
  // ---- sup2 path: sup2 = 2*(sup@sup) - I, bf16 row-major ----
  {
    int mg0 = blockIdx.y * 8, ng0 = blockIdx.x * 8;
    constexpr int Kg = 32, Ng = 64;
    u16* As = smem;
    u16* Bs = smem + 8192;
    f32x4 acc1[4][4] = {};
    for (int k0 = 0; k0 < Kg; k0 += 2) {
      __syncthreads();
      #pragma unroll
      for (int i = 0; i < 4; i++) {
        int f = w + 4*i;
        int r = f >> 1, c = f & 1;
        size_t goff = (((size_t)(mg0 + r)) * Kg + (k0 + c)) * 512 + (lane << 3);
        gl_lds16(supA + goff, &As[f * 512]);
        int cb = f >> 3, tn = f & 7;
        size_t boff = (((size_t)(k0 + cb)) * Ng + (ng0 + tn)) * 512 + (lane << 3);
        gl_lds16(supB + boff, &Bs[f * 512]);
      }
      __syncthreads();
      #pragma unroll
      for (int kk = 0; kk < 2; kk++) {
        short8v bq[4], av[4];
        #pragma unroll
        for (int j = 0; j < 4; j++)
          bq[j] = *(const short8v*)&Bs[(kk*8 + wc*4 + j)*512 + (lane << 3)];
        #pragma unroll
        for (int i = 0; i < 4; i++)
          av[i] = *(const short8v*)&As[((wr*4 + i)*2 + kk)*512 + (lane << 3)];
        #pragma unroll
        for (int i = 0; i < 4; i++)
          #pragma unroll
          for (int j = 0; j < 4; j++)
            acc1[i][j] = __builtin_amdgcn_mfma_f32_16x16x32_bf16(av[i], bq[j], acc1[i][j], 0, 0, 0);
      }
    }
    #pragma unroll
    for (int i = 0; i < 4; i++) {
      int row = (mg0 + wr*4 + i)*16 + (hi << 2);
      #pragma unroll
      for (int j = 0; j < 4; j++) {
        int col = (ng0 + wc*4 + j)*16 + lm;
        #pragma unroll
        for (int r = 0; r < 4; r++)
          sup2D[(size_t)(row + r)*N_ + col] =
              f2bf(2.f*acc1[i][j][r] - ((row + r) == col ? 1.f : 0.f));
      }
    }
  }
}

// ---------------- pack s_v + supports(A/B/rowmajor) + weights + colmax zero ----------------
__global__ void k_pack_sv(const float* __restrict__ sv, u16* __restrict__ svp,
                          const float* __restrict__ sup, u16* __restrict__ supA,
                          u16* __restrict__ supB, u16* __restrict__ supR,
                          const float* __restrict__ gcn_w, const float* __restrict__ time_w,
                          const float* __restrict__ conv1_w, u16* __restrict__ WAp,
                          u16* __restrict__ W2p, unsigned* __restrict__ cmz) {
  int t = blockIdx.x * 256 + threadIdx.x;            // 131072
  int fi = t >> 6, l = t & 63;
  int mg = fi >> 5, kg = fi & 31;
  int row = (mg << 4) + (l & 15);
  int k   = (kg << 5) + ((l >> 4) << 3);
  {
    const float* s = sv + (size_t)row*N_ + k;
    const float* s2 = sup + (size_t)row*N_ + k;
    u16* d  = svp  + ((size_t)fi << 9) + (l << 3);
    u16* dA = supA + ((size_t)fi << 9) + (l << 3);
    u16* dR = supR + (size_t)row*N_ + k;
    #pragma unroll
    for (int j = 0; j < 8; j++) {
      u16 bv = f2bf(s2[j]);
      d[j] = f2bf(s[j]); dA[j] = bv; dR[j] = bv;
    }
  }
  {
    int kgB = fi >> 6, nbB = fi & 63;
    int colB = (nbB << 4) + (l & 15);
    int krB  = (kgB << 5) + ((l >> 4) << 3);
    u16* dB = supB + ((size_t)fi << 9) + (l << 3);
    #pragma unroll
    for (int j = 0; j < 8; j++) dB[j] = f2bf(sup[(size_t)(krB + j)*N_ + colB]);
  }
  if (t < 16384) cmz[t] = 0u;
  if (t < 6144) {
    int fi2 = t >> 9, l2 = (t >> 3) & 63, j2 = t & 7;
    int kg2 = fi2 >> 2, cf = fi2 & 3;
    int o = cf*16 + (l2 & 15), c = ((l2 >> 4) << 3) + j2;
    WAp[t] = f2bf(gcn_w[o*96 + c*3 + kg2]);
  }
  if (t < 14336) {
    int fi2 = t >> 9, l2 = (t >> 3) & 63, j2 = t & 7;
    int kg2 = fi2 >> 2, cf = fi2 & 3;
    int o2 = cf*16 + (l2 & 15), kk = ((l2 >> 4) << 3) + j2;
    float v;
    if (kg2 < 6) { int tt2 = kg2 >> 1, i = (kg2 & 1)*32 + kk; v = time_w[o2*192 + i*3 + tt2]; }
    else v = conv1_w[o2*32 + kk];
    W2p[t] = f2bf(v);
  }
}

// ---------------- logits GEMM: 8-wave 128x256, 3-buf counted-vmcnt, bf16 out, colmax ----------------
__global__ __launch_bounds__(512) void k_logits(
    const u16* __restrict__ Ap, const u16* __restrict__ Bp,
    u16* __restrict__ lgb, unsigned* __restrict__ cmg) {
  int hw = blockIdx.x + (blockIdx.y << 2) + (blockIdx.z << 5);   // grid (4,8,16)
  int logical = (hw & 7)*64 + (hw >> 3);                         // bijective (512%8==0)
  int ng0 = (logical & 3) * 16;
  int mg0 = ((logical >> 2) & 7) * 8;
  int b   = logical >> 5;
  const u16* A1 = Ap;
  const u16* Bm = Bp + ((size_t)b << 20);
  constexpr int Kg = 32, Ng = 64;
  int tid = threadIdx.x;
  int w = tid >> 6, lane = tid & 63;
  int r2 = w >> 2, c4 = w & 3;
  int lm = lane & 15, hi = lane >> 4;
  __shared__ __align__(16) u16 smem[3 * 12288];
  f32x4 acc[4][4] = {};
  #define LG_STAGE(kg, buf) {                                                   \
    u16* dst = smem + (buf)*12288;                                              \
    size_t goffA = (((size_t)(mg0 + w)) * Kg + (kg)) * 512 + (lane << 3);       \
    gl_lds16(A1 + goffA, &dst[w*512]);                                          \
    size_t bo0 = (((size_t)(kg)) * Ng + (ng0 + w)) * 512 + (lane << 3);         \
    gl_lds16(Bm + bo0, &dst[4096 + w*512]);                                     \
    size_t bo1 = (((size_t)(kg)) * Ng + (ng0 + w + 8)) * 512 + (lane << 3);     \
    gl_lds16(Bm + bo1, &dst[4096 + (w + 8)*512]);                               \
  }
  LG_STAGE(0, 0);
  LG_STAGE(1, 1);
  for (int kg = 0; kg < Kg; kg++) {
    int cur = kg % 3;
    if (kg + 2 < Kg) {
      LG_STAGE(kg + 2, (kg + 2) % 3);
      asm volatile("s_waitcnt vmcnt(6)" ::: "memory");   // cur retired; next two in flight
    } else if (kg + 1 < Kg) {
      asm volatile("s_waitcnt vmcnt(3)" ::: "memory");
    } else {
      asm volatile("s_waitcnt vmcnt(0)" ::: "memory");
    }
    __builtin_amdgcn_s_barrier();
    __builtin_amdgcn_sched_barrier(0);
    const u16* Asrc = smem + cur*12288;
    const u16* Bsrc = Asrc + 4096;
    short8v bq[4];
    #pragma unroll
    for (int j = 0; j < 4; j++)
      bq[j] = *(const short8v*)&Bsrc[(c4*4 + j)*512 + (lane << 3)];
    __builtin_amdgcn_s_setprio(1);
    #pragma unroll
    for (int i = 0; i < 4; i++) {
      short8v av = *(const short8v*)&Asrc[(r2*4 + i)*512 + (lane << 3)];
      #pragma unroll
      for (int j = 0; j < 4; j++)
        acc[i][j] = __builtin_amdgcn_mfma_f32_16x16x32_bf16(av, bq[j], acc[i][j], 0, 0, 0);
    }
    __builtin_amdgcn_s_setprio(0);
    asm volatile("" ::: "memory");
    __builtin_amdgcn_s_barrier();
  }
  #undef LG_STAGE
  __shared__ unsigned cmL[256];
  if (tid < 256) cmL[tid] = 0u;
  __syncthreads();
  #pragma unroll
  for (int j = 0; j < 4; j++) {
    float m = -3.4e38f;
    #pragma unroll
    for (int i = 0; i < 4; i++)
      #pragma unroll
      for (int r = 0; r < 4; r++) m = fmaxf(m, acc[i][j][r]);
    m = fmaxf(m, __shfl_xor(m, 16));
    m = fmaxf(m, __shfl_xor(m, 32));
    if (hi == 0)
      atomicMax(&cmL[(c4*4 + j)*16 + lm], fkey(m));
  }
  __syncthreads();
  if (tid < 256)
    atomicMax(&cmg[(size_t)b*N_ + ng0*16 + tid], cmL[tid]);
  u16* d1 = lgb + ((size_t)b << 20);
  #pragma unroll
  for (int i = 0; i < 4; i++) {
    int row = (mg0 + r2*4 + i)*16 + (hi << 2);
    #pragma unroll
    for (int j = 0; j < 4; j++) {
      int col = (ng0 + c4*4 + j)*16 + lm;
      #pragma unroll
      for (int r = 0; r < 4; r++)
        d1[(size_t)(row + r)*N_ + col] = f2bf(acc[i][j][r]);
    }
  }
}

// ---------------- fused: row softmax + S_coef + A1/A2 pack (bf16 sup reads) + pad ----------------
__global__ __launch_bounds__(256) void k_smpk(const u16* __restrict__ lgb,
    float* __restrict__ Sout, const unsigned* __restrict__ cm,
    const u16* __restrict__ supR, const u16* __restrict__ sup2B,
    u16* __restrict__ A1p, u16* __restrict__ A2p, u16* __restrict__ gcnB) {
  int bm = blockIdx.x;                               // b*1024 + row
  int b = bm >> 10, row = bm & 1023;
  int t = threadIdx.x;
  int k0 = t * 4;
  const unsigned* cmb = cm + (size_t)b * N_;
  short4v l4 = *(const short4v*)&lgb[(size_t)bm * N_ + k0];
  float v[4];
  #pragma unroll
  for (int j = 0; j < 4; j++) v[j] = bf2f((u16)l4[j]) - funkey(cmb[k0 + j]);
  float mx = fmaxf(fmaxf(v[0], v[1]), fmaxf(v[2], v[3]));
  #pragma unroll
  for (int off = 32; off; off >>= 1) mx = fmaxf(mx, __shfl_down(mx, off));
  __shared__ float sm[4], ss[4];
  int w = t >> 6, lane = t & 63;
  if (lane == 0) sm[w] = mx;
  __syncthreads();
  mx = fmaxf(fmaxf(sm[0], sm[1]), fmaxf(sm[2], sm[3]));
  float e[4]; float s = 0.f;
  #pragma unroll
  for (int j = 0; j < 4; j++) { e[j] = expf(v[j] - mx); s += e[j]; }
  #pragma unroll
  for (int off = 32; off; off >>= 1) s += __shfl_down(s, off);
  if (lane == 0) ss[w] = s;
  __syncthreads();
  float inv = 1.f / (ss[0] + ss[1] + ss[2] + ss[3]);
  float p[4];
  #pragma unroll
  for (int j = 0; j < 4; j++) p[j] = e[j] * inv;
  *(float4*)&Sout[(size_t)bm * N_ + k0] = make_float4(p[0], p[1], p[2], p[3]);
  short4v s1v = *(const short4v*)&supR[(size_t)row*N_ + k0];
  short4v s2v = *(const short4v*)&sup2B[(size_t)row*N_ + k0];
  unsigned fi = (unsigned)((row >> 4) << 5) | (unsigned)(k0 >> 5);
  unsigned lp = (unsigned)(row & 15) | ((unsigned)((k0 >> 3) & 3) << 4);
  size_t dst = ((size_t)b << 20) + ((size_t)fi << 9) + (lp << 3) + (k0 & 7);
  u16 o1[4], o2[4];
  #pragma unroll
  for (int j = 0; j < 4; j++) {
    o1[j] = f2bf(p[j] * bf2f((u16)s1v[j]));
    o2[j] = f2bf(p[j] * bf2f((u16)s2v[j]));
  }
  *(unsigned long long*)&A1p[dst] = *(unsigned long long*)o1;
  *(unsigned long long*)&A2p[dst] = *(unsigned long long*)o2;
  if (t < 32) {
    size_t po = ((size_t)bm*26 + (t >> 4)*25)*64 + (t & 15)*4;
    *(unsigned long long*)&gcnB[po] = 0ull;
  }
}

// ---------------- x_TAt: 8-node blocks, reads bf16 xr, coalesced writes ----------------
__global__ __launch_bounds__(768) void k_xtat8(const u16* __restrict__ xr,
    const float* __restrict__ Tout, u16* __restrict__ xTlc,
    u16* __restrict__ Xp) {
  int blk = blockIdx.x;                              // B*128
  int b = blk >> 7, n0 = (blk & 127) << 3;
  __shared__ float xs[6400];                         // [nl][c*25 + l]
  __shared__ float Tl[576];
  int tid = threadIdx.x;
  const u16* xrb = xr + (size_t)(b*N_ + n0)*768;
  #pragma unroll
  for (int nl = 0; nl < 8; nl++) {
    u16 v = xrb[(size_t)nl*768 + tid];
    int l = tid >> 5, c = tid & 31;
    xs[nl*800 + c*25 + l] = bf2f(v);
  }
  if (tid < 576) Tl[tid] = Tout[(size_t)b*576 + tid];
  __syncthreads();
  int q = tid >> 5, cc = tid & 31;
  u16 xp8[8];
  #pragma unroll
  for (int nl = 0; nl < 8; nl++) {
    const float* xsn = &xs[nl*800 + cc*25];
    float acc = 0.f;
    #pragma unroll
    for (int ll = 0; ll < 24; ll++) acc += xsn[ll] * Tl[ll*24 + q];
    u16 bv = f2bf(acc);
    size_t bn = (size_t)b*N_ + n0 + nl;
    xTlc[bn*768 + tid] = bv;
    xp8[nl] = bv;
  }
  int fi = (n0 >> 5)*48 + (tid >> 4);
  int lidx = (tid & 15) | (((n0 >> 3) & 3) << 4);
  *(short8v*)&Xp[(size_t)b*786432 + (size_t)fi*512 + lidx*8] = *(short8v*)xp8;
}

// ---------------- fused Chebyshev dual GEMM + GA — 8-wave, 3-buf counted-vmcnt ----------------
__global__ __launch_bounds__(512) void k_chga(
    const u16* __restrict__ A1p, const u16* __restrict__ A2p,
    const u16* __restrict__ Bp, const u16* __restrict__ xTlc,
    const float* __restrict__ S, const u16* __restrict__ WAp,
    const float* __restrict__ gcn_b, u16* __restrict__ gcn) {
  int hw = blockIdx.x + 6*blockIdx.y + 48*blockIdx.z;  // grid (6,8,16)
  int logical = (hw & 7)*96 + (hw >> 3);               // bijective
  int tx = logical % 6; int tmp = logical / 6;
  int ty = tmp & 7; int b = tmp >> 3;
  const u16* A1 = A1p + ((size_t)b << 20);
  const u16* A2 = A2p + ((size_t)b << 20);
  const u16* Bm = Bp + (size_t)b * 786432;
  int mg0 = ty * 8;
  int ng0 = tx * 8;
  int l0 = tx * 4;
  constexpr int Kg = 32, Ng = 48;
  int tid = threadIdx.x;
  int w = tid >> 6, lane = tid & 63;
  int m  = w & 1;
  int c2 = (w >> 1) & 1;
  int r2 = w >> 2;
  int lm = lane & 15, hi = lane >> 4;
  __shared__ __align__(16) u16 smem[3 * 12288];
  f32x4 acc[4][4] = {};
  #define CH_STAGE(kg, buf) {                                                   \
    u16* dst = smem + (buf)*12288;                                              \
    size_t goffA = (((size_t)(mg0 + w)) * Kg + (kg)) * 512 + (lane << 3);       \
    gl_lds16(A1 + goffA, &dst[w*512]);                                          \
    gl_lds16(A2 + goffA, &dst[4096 + w*512]);                                   \
    size_t bo = (((size_t)(kg)) * Ng + (ng0 + w)) * 512 + (lane << 3);          \
    gl_lds16(Bm + bo, &dst[8192 + w*512]);                                      \
  }
  CH_STAGE(0, 0);
  CH_STAGE(1, 1);
  for (int kg = 0; kg < Kg; kg++) {
    int cur = kg % 3;
    if (kg + 2 < Kg) {
      CH_STAGE(kg + 2, (kg + 2) % 3);
      asm volatile("s_waitcnt vmcnt(6)" ::: "memory");   // cur retired; next two in flight
    } else if (kg + 1 < Kg) {
      asm volatile("s_waitcnt vmcnt(3)" ::: "memory");
    } else {
      asm volatile("s_waitcnt vmcnt(0)" ::: "memory");
    }
    __builtin_amdgcn_s_barrier();
    __builtin_amdgcn_sched_barrier(0);
    const u16* base = smem + cur*12288;
    const u16* Asrc = base + (m ? 4096 : 0);
    const u16* Bsrc = base + 8192;
    short8v bq[4];
    #pragma unroll
    for (int j = 0; j < 4; j++)
      bq[j] = *(const short8v*)&Bsrc[(c2*4 + j)*512 + (lane << 3)];
    __builtin_amdgcn_s_setprio(1);
    #pragma unroll
    for (int i = 0; i < 4; i++) {
      short8v av = *(const short8v*)&Asrc[(r2*4 + i)*512 + (lane << 3)];
      #pragma unroll
      for (int j = 0; j < 4; j++)
        acc[i][j] = __builtin_amdgcn_mfma_f32_16x16x32_bf16(av, bq[j], acc[i][j], 0, 0, 0);
    }
    __builtin_amdgcn_s_setprio(0);
    asm volatile("" ::: "memory");
    __builtin_amdgcn_s_barrier();
  }
  #undef CH_STAGE
  // ---- GA phase ----
  u16* zL  = smem;
  u16* wsm = smem + 18432;
  float gb[4];
  #pragma unroll
  for (int cf = 0; cf < 4; cf++) gb[cf] = gcn_b[cf*16 + lm];
  #pragma unroll
  for (int ch = 0; ch < 2; ch++) {
    __syncthreads();
    if (ch == 0) {
      gl_lds16(WAp + w*512 + (lane << 3), &wsm[w*512 + (lane << 3)]);
      if (w < 4)
        gl_lds16(WAp + (8 + w)*512 + (lane << 3), &wsm[(8 + w)*512 + (lane << 3)]);
    }
    if (r2 == ch) {
      #pragma unroll
      for (int i = 0; i < 4; i++)
        #pragma unroll
        for (int j = 0; j < 4; j++) {
          int col = (c2*4 + j)*16 + lm;
          int ll = col >> 5, c = col & 31;
          #pragma unroll
          for (int r = 0; r < 4; r++) {
            int lr = (i*16 + hi*4 + r)*4 + ll;
            int za = lr*36 + ((((c >> 3) + (lr >> 4)) & 3) << 3) + (c & 7);
            zL[m*9216 + za] = f2bf(acc[i][j][r]);
          }
        }
    }
    __syncthreads();
    #pragma unroll
    for (int gg = 0; gg < 2; gg++) {
      int g = w*2 + gg;
      int lr = g*16 + lm;
      int grow = ch*256 + lr;
      int nl = mg0*16 + (grow >> 2);
      int ll = l0 + (grow & 3);
      short8v a0 = *(const short8v*)&xTlc[(size_t)b*786432 + ((size_t)nl*24 + ll)*32 + hi*8];
      float sd = S[((size_t)b << 20) + (size_t)nl*1025];
      #pragma unroll
      for (int jj = 0; jj < 8; jj++)
        a0[jj] = (short)f2bf(bf2f((u16)a0[jj]) * sd);
      int slot = (hi + g) & 3;
      const u16* zp = &zL[lr*36 + slot*8];
      short4v z1lo = *(const short4v*)zp;
      short4v z1hi = *(const short4v*)(zp + 4);
      short4v z2lo = *(const short4v*)(zp + 9216);
      short4v z2hi = *(const short4v*)(zp + 9220);
      short8v a1 = {z1lo[0], z1lo[1], z1lo[2], z1lo[3], z1hi[0], z1hi[1], z1hi[2], z1hi[3]};
      short8v a2 = {z2lo[0], z2lo[1], z2lo[2], z2lo[3], z2hi[0], z2hi[1], z2hi[2], z2hi[3]};
      #pragma unroll
      for (int cf = 0; cf < 4; cf++) {
        short8v w0 = *(const short8v*)&wsm[(0*4 + cf)*512 + (lane << 3)];
        short8v w1 = *(const short8v*)&wsm[(1*4 + cf)*512 + (lane << 3)];
        short8v w2 = *(const short8v*)&wsm[(2*4 + cf)*512 + (lane << 3)];
        f32x4 a = {};
        a = __builtin_amdgcn_mfma_f32_16x16x32_bf16(a0, w0, a, 0, 0, 0);
        a = __builtin_amdgcn_mfma_f32_16x16x32_bf16(a1, w1, a, 0, 0, 0);
        a = __builtin_amdgcn_mfma_f32_16x16x32_bf16(a2, w2, a, 0, 0, 0);
        int o = cf*16 + lm;
        #pragma unroll
        for (int r = 0; r < 4; r++) {
          int gr2 = ch*256 + g*16 + hi*4 + r;
          int n2 = mg0*16 + (gr2 >> 2);
          int l2 = l0 + (gr2 & 3);
          gcn[(((size_t)b*1024 + n2)*26 + l2 + 1)*64 + o] =
              f2bf(fmaxf(a[r] + gb[cf], 0.f));
        }
      }
    }
  }
}

// ---------------- GB: pre -> bf16 staging + LN partials ----------------
__global__ __launch_bounds__(256) void k_gb(const u16* __restrict__ gcn,
    const u16* __restrict__ xr, const u16* __restrict__ W2p,
    const float* __restrict__ time_b, const float* __restrict__ conv1_b,
    u16* __restrict__ preB, float* __restrict__ partials) {
  int blk = blockIdx.x;
  int b = blk / 192, mt = blk % 192;
  int tid = threadIdx.x, w = tid >> 6, lane = tid & 63;
  int lm = lane & 15, hi = lane >> 4;
  f32x4 acc[2][4] = {};
  #pragma unroll
  for (int g = 0; g < 7; g++) {
    short8v Bf[4];
    #pragma unroll
    for (int cf = 0; cf < 4; cf++)
      Bf[cf] = *(const short8v*)&W2p[(g*4 + cf)*512 + lane*8];
    #pragma unroll
    for (int rf = 0; rf < 2; rf++) {
      int row = mt*128 + (w*2 + rf)*16 + lm;
      short8v a;
      if (g < 6) {
        int n = row / 24, l = row - 24*n;
        int ts = g >> 1, o0 = (g & 1)*32;
        a = *(const short8v*)&gcn[(((size_t)b*1024 + n)*26 + l + ts)*64 + o0 + hi*8];
      } else {
        a = *(const short8v*)&xr[(size_t)b*786432 + (size_t)row*32 + hi*8];
      }
      #pragma unroll
      for (int cf = 0; cf < 4; cf++)
        acc[rf][cf] = __builtin_amdgcn_mfma_f32_16x16x32_bf16(a, Bf[cf], acc[rf][cf], 0, 0, 0);
    }
  }
  float s1 = 0.f, s2 = 0.f;
  #pragma unroll
  for (int rf = 0; rf < 2; rf++) {
    int rbase = mt*128 + (w*2 + rf)*16 + hi*4;
    int n = rbase / 24, l0 = rbase - 24*n;
    #pragma unroll
    for (int cf = 0; cf < 4; cf++) {
      int o2 = cf*16 + lm;
      float bias = time_b[o2] + conv1_b[o2];
      u16 ov[4];
      #pragma unroll
      for (int r = 0; r < 4; r++) {
        float pre = fmaxf(acc[rf][cf][r] + bias, 0.f);
        s1 += pre; s2 += pre*pre; ov[r] = f2bf(pre);
      }
      *(unsigned long long*)&preB[(((size_t)b*64 + o2)*1024 + n)*24 + l0] =
          *(unsigned long long*)ov;
    }
  }
  #pragma unroll
  for (int off = 32; off; off >>= 1) { s1 += __shfl_down(s1, off); s2 += __shfl_down(s2, off); }
  __shared__ float red[8];
  if (lane == 0) { red[w*2] = s1; red[w*2 + 1] = s2; }
  __syncthreads();
  if (tid == 0) {
    float t1 = 0.f, t2 = 0.f;
    for (int ww = 0; ww < 4; ww++) { t1 += red[ww*2]; t2 += red[ww*2 + 1]; }
    partials[blk*2] = t1; partials[blk*2 + 1] = t2;
  }
}

__global__ __launch_bounds__(256) void k_bstats(const float* __restrict__ partials,
                                                float* __restrict__ bstats) {
  int b = blockIdx.x; int tid = threadIdx.x;
  __shared__ float r1[256], r2[256];
  r1[tid] = (tid < 192) ? partials[(b*192 + tid)*2] : 0.f;
  r2[tid] = (tid < 192) ? partials[(b*192 + tid)*2 + 1] : 0.f;
  __syncthreads();
  for (int off = 128; off; off >>= 1) {
    if (tid < off) { r1[tid] += r1[tid + off]; r2[tid] += r2[tid + off]; }
    __syncthreads();
  }
  if (tid == 0) { bstats[b*2] = r1[0]; bstats[b*2 + 1] = r2[0]; }
}

__global__ void k_ln4(const u16* __restrict__ preB, float4* __restrict__ out,
                      const float* __restrict__ bstats,
                      const float4* __restrict__ lnw, const float4* __restrict__ lnb) {
  constexpr size_t PER4 = (size_t)CO_*N_*L_/4;
  size_t i = (size_t)blockIdx.x * 256 + threadIdx.x;
  int b = (int)(i / PER4); size_t r = i % PER4;
  float cnt = (float)(PER4*4);
  float mu = bstats[b*2] / cnt;
  float var = bstats[b*2 + 1] / cnt - mu*mu;
  float inv = rsqrtf(var + 1e-5f);
  short4v p4 = *(const short4v*)&preB[i*4];
  float4 w = lnw[r], bb = lnb[r];
  float4 o;
  o.x = (bf2f((u16)p4[0]) - mu)*inv*w.x + bb.x;
  o.y = (bf2f((u16)p4[1]) - mu)*inv*w.y + bb.y;
  o.z = (bf2f((u16)p4[2]) - mu)*inv*w.z + bb.z;
  o.w = (bf2f((u16)p4[3]) - mu)*inv*w.w + bb.w;
  out[i] = o;
}
} // namespace

extern "C" void kernel_launch(void* const* d_in, const int* in_sizes, int n_in,
                              void* d_out, int out_size, void* d_ws, size_t ws_size,
                              hipStream_t stream) {
  const float* x        = (const float*)d_in[0];
  const float* supports = (const float*)d_in[1];
  const float* conv1_w  = (const float*)d_in[2];
  const float* conv1_b  = (const float*)d_in[3];
  const float* t1w      = (const float*)d_in[4];
  const float* t2w      = (const float*)d_in[5];
  const float* t_w      = (const float*)d_in[6];
  const float* t_b      = (const float*)d_in[7];
  const float* t_v      = (const float*)d_in[8];
  const float* s1w      = (const float*)d_in[9];
  const float* s2w      = (const float*)d_in[10];
  const float* s_w      = (const float*)d_in[11];
  const float* s_b      = (const float*)d_in[12];
  const float* s_v      = (const float*)d_in[13];
  const float* gcn_w    = (const float*)d_in[14];
  const float* gcn_b    = (const float*)d_in[15];
  const float* time_w   = (const float*)d_in[16];
  const float* time_b   = (const float*)d_in[17];
  const float* ln_w     = (const float*)d_in[18];
  const float* ln_b     = (const float*)d_in[19];

  float* out  = (float*)d_out;
  float* Sout = out + S_OFF;
  float* Tout = out + T_OFF;
  u16*   outU = (u16*)d_out;
  float* ws   = (float*)d_ws;

  u16*   gcnB = (u16*)(ws + O_GCN);
  u16*   rawp = (u16*)(ws + O_GCN);      // alias: dead before gcnB written
  u16*   xTlc = (u16*)(ws + O_XTLC);
  u16*   xr   = (u16*)(ws + O_XR);
  u16*   supB = (u16*)(ws + O_SUPB);
  u16*   lgb  = (u16*)(ws + O_LGB);
  float* part2= ws + O_LGB;              // alias: consumed before lgb written
  u16*   preB = (u16*)(ws + O_LGB);      // alias: lgb/f1t dead before k_gb writes
  float* f1t  = ws + O_F1T;
  float* f2t  = ws + O_F2T;
  u16*   f2p  = (u16*)(ws + O_F2S);
  float* g_t  = ws + O_GT;
  u16*   gsp  = (u16*)(ws + O_GS);
  unsigned* cm = (unsigned*)(ws + O_CM);
  u16*   WAp  = (u16*)(ws + O_WAP);
  u16*   W2p  = (u16*)(ws + O_W2P);
  float* part = ws + O_PART;
  float* bst  = ws + O_BST;

  u16*   A1p  = outU + OS_A1;
  u16*   A2p  = outU + OS_A2;
  u16*   Xp   = outU + OS_XP;
  u16*   svp  = outU + OS_SV;
  u16*   sup2B= outU + OS_SUP2;
  u16*   supR = outU + OS_SUPR;
  u16*   supA = outU + OS_SUPA;

  k_ff<<<2048, 256, 0, stream>>>(x, t1w, s1w, s2w, t2w, s_w, f1t, gsp, f2p, part2, xr);
  k_aux<<<432, 256, 0, stream>>>(part2, f2t, f1t, t_w, g_t);
  k_tatt<<<B_, 576, 0, stream>>>(g_t, f2t, t_b, t_v, Tout);
  k_pack_sv<<<512, 256, 0, stream>>>(s_v, svp, supports, supA, supB, supR,
                                     gcn_w, time_w, conv1_w, WAp, W2p, cm);
  // merged raw_s MFMA (z<16) + sup2 GEMM (z==16)
  k_rsup<<<dim3(8, 8, 17), 256, 0, stream>>>(gsp, f2p, s_b, rawp, supA, supB, sup2B);
  k_logits<<<dim3(4, 8, B_), 512, 0, stream>>>(svp, rawp, lgb, cm);
  k_smpk<<<B_*N_, 256, 0, stream>>>(lgb, Sout, cm, supR, sup2B, A1p, A2p, gcnB);
  k_xtat8<<<2048, 768, 0, stream>>>(xr, Tout, xTlc, Xp);
  k_chga<<<dim3(6, 8, B_), 512, 0, stream>>>(A1p, A2p, Xp, xTlc, Sout, WAp, gcn_b, gcnB);
  k_gb<<<3072, 256, 0, stream>>>(gcnB, xr, W2p, time_b, conv1_b, preB, part);
  k_bstats<<<B_, 256, 0, stream>>>(part, bst);
  k_ln4<<<24576, 256, 0, stream>>>(preB, (float4*)out, bst,
                                   (const float4*)ln_w, (const float4*)ln_b);
}